// Round 8
// baseline (102.651 us; speedup 1.0000x reference)
//
#include <hip/hip_runtime.h>

#define NH 16

using hfrag = __attribute__((ext_vector_type(8))) _Float16;
using f4v   = __attribute__((ext_vector_type(4))) float;

// ---------------------------------------------------------------------------
// Merged prep:
//   blocks [0,2048):    W3 (128k x 16384f f32) -> w3t (16384f x 128k fp16,
//                       pre-scaled by log2e so softmax uses raw v_exp_f32)
//   blocks [2048,3072): x -> xT
//   blocks [3072,3136): xms[n,d] = sum_{l masked} x[n,l,d], nmask[n] = #masked
// ---------------------------------------------------------------------------
__global__ __launch_bounds__(256) void prep_kernel(
    const float* __restrict__ W3, _Float16* __restrict__ w3t,
    const float* __restrict__ x, float* __restrict__ xT,
    const float* __restrict__ maskx, float* __restrict__ xms,
    float* __restrict__ nmask) {
  __shared__ float t[32][33];
  __shared__ float sm2[2][128];
  const int bid = blockIdx.x;
  const int tx = threadIdx.x & 31, ty = threadIdx.x >> 5;  // ty 0..7
  if (bid < 2048) {
    const int f0 = (bid & 511) * 32;
    const int k0 = (bid >> 9) * 32;
#pragma unroll
    for (int i = 0; i < 4; ++i)
      t[ty + 8 * i][tx] = W3[(size_t)(k0 + ty + 8 * i) * 16384 + f0 + tx];
    __syncthreads();
#pragma unroll
    for (int i = 0; i < 4; ++i)
      w3t[(size_t)(f0 + ty + 8 * i) * 128 + k0 + tx] =
          (_Float16)(t[tx][ty + 8 * i] * 1.44269504f);
  } else if (bid < 3072) {
    const int b2 = bid - 2048;
    const int d0 = (b2 & 3) * 32, l0 = ((b2 >> 2) & 3) * 32, n = b2 >> 4;
    const size_t base = (size_t)n * 16384;
#pragma unroll
    for (int i = 0; i < 4; ++i)
      t[ty + 8 * i][tx] = x[base + (size_t)(l0 + ty + 8 * i) * 128 + d0 + tx];
    __syncthreads();
#pragma unroll
    for (int i = 0; i < 4; ++i)
      xT[base + (size_t)(d0 + ty + 8 * i) * 128 + l0 + tx] = t[tx][ty + 8 * i];
  } else {
    const int n = bid - 3072;
    const int d = threadIdx.x & 127, seg = threadIdx.x >> 7;
    const float* xn = x + (size_t)n * 16384;
    const float* mn = maskx + n * 128;
    float acc = 0.f;
#pragma unroll 8
    for (int l = seg * 64; l < seg * 64 + 64; ++l)
      acc += (mn[l] == 0.f) ? xn[l * 128 + d] : 0.f;
    sm2[seg][d] = acc;
    __syncthreads();
    if (threadIdx.x < 128) xms[n * 128 + d] = sm2[0][d] + sm2[1][d];
    if (threadIdx.x == 0) {
      float c = 0.f;
      for (int l = 0; l < 128; ++l) c += (mn[l] == 0.f) ? 1.f : 0.f;
      nmask[n] = c;
    }
  }
}

// ---------------------------------------------------------------------------
// MLP: h2 = relu(relu(x@W1+b1)@W2+b2) * mask -> fp16. Masked l-rows are
// zeroed here so the fused kernel needs no per-element mask logic.
// grid (64 n, 4 lq), 256 thr.
// ---------------------------------------------------------------------------
__global__ __launch_bounds__(256) void mlp2_kernel(
    const float* __restrict__ x, const float* __restrict__ W1,
    const float* __restrict__ b1, const float* __restrict__ W2,
    const float* __restrict__ b2, const float* __restrict__ maskx,
    _Float16* __restrict__ h2f) {
  __shared__ float wbuf[128 * 128];   // 64 KB weights
  __shared__ float abuf[32 * 132];    // padded activations
  const int n = blockIdx.x, lq = blockIdx.y;
  const int tid = threadIdx.x;

  {
    const float4* wsrc = (const float4*)W1;
    float4* wdst = (float4*)wbuf;
#pragma unroll
    for (int i = 0; i < 16; ++i) wdst[tid + 256 * i] = wsrc[tid + 256 * i];
    const float4* xsrc = (const float4*)(x + (size_t)n * 16384 + lq * 32 * 128);
#pragma unroll
    for (int i = 0; i < 4; ++i) {
      int idx = tid + 256 * i;
      int row = idx >> 5, c4 = idx & 31;
      *(float4*)&abuf[row * 132 + c4 * 4] = xsrc[idx];
    }
  }
  __syncthreads();

  const int tl = tid >> 4, td = tid & 15;
  const int r0 = tl * 2, j0 = td * 8;
  const float m0 = maskx[n * 128 + lq * 32 + r0 + 0];
  const float m1 = maskx[n * 128 + lq * 32 + r0 + 1];
  float s[2][8];

#pragma unroll
  for (int i = 0; i < 2; ++i)
#pragma unroll
    for (int j = 0; j < 8; ++j) s[i][j] = 0.f;
#pragma unroll 4
  for (int k = 0; k < 128; ++k) {
    float a0 = abuf[(r0 + 0) * 132 + k];
    float a1 = abuf[(r0 + 1) * 132 + k];
    float4 bv0 = *(const float4*)&wbuf[k * 128 + j0];
    float4 bv1 = *(const float4*)&wbuf[k * 128 + j0 + 4];
    float b[8] = {bv0.x, bv0.y, bv0.z, bv0.w, bv1.x, bv1.y, bv1.z, bv1.w};
#pragma unroll
    for (int j = 0; j < 8; ++j) {
      s[0][j] += a0 * b[j];
      s[1][j] += a1 * b[j];
    }
  }
  __syncthreads();

#pragma unroll
  for (int i = 0; i < 2; ++i)
#pragma unroll
    for (int j = 0; j < 8; ++j)
      abuf[(r0 + i) * 132 + j0 + j] = fmaxf(s[i][j] + b1[j0 + j], 0.f);
  {
    const float4* wsrc = (const float4*)W2;
    float4* wdst = (float4*)wbuf;
#pragma unroll
    for (int i = 0; i < 16; ++i) wdst[tid + 256 * i] = wsrc[tid + 256 * i];
  }
  __syncthreads();

#pragma unroll
  for (int i = 0; i < 2; ++i)
#pragma unroll
    for (int j = 0; j < 8; ++j) s[i][j] = 0.f;
#pragma unroll 4
  for (int k = 0; k < 128; ++k) {
    float a0 = abuf[(r0 + 0) * 132 + k];
    float a1 = abuf[(r0 + 1) * 132 + k];
    float4 bv0 = *(const float4*)&wbuf[k * 128 + j0];
    float4 bv1 = *(const float4*)&wbuf[k * 128 + j0 + 4];
    float b[8] = {bv0.x, bv0.y, bv0.z, bv0.w, bv1.x, bv1.y, bv1.z, bv1.w};
#pragma unroll
    for (int j = 0; j < 8; ++j) {
      s[0][j] += a0 * b[j];
      s[1][j] += a1 * b[j];
    }
  }

  const float mm[2] = {m0, m1};
  const size_t obase = (size_t)n * 16384 + (size_t)(lq * 32) * 128;
#pragma unroll
  for (int i = 0; i < 2; ++i)
#pragma unroll
    for (int j = 0; j < 8; ++j)
      h2f[obase + (size_t)(r0 + i) * 128 + j0 + j] =
          (_Float16)(fmaxf(s[i][j] + b2[j0 + j], 0.f) * mm[i]);
}

// ---------------------------------------------------------------------------
// Fused: 512 thr, 8 waves = 2 l-halves x 4 col-groups; 16 h per block,
// grid (64,8) = 512 blocks. LDS = 32 KB A + 32 KB wp = 64 KB ->
// 2 blocks/CU, 4 waves/SIMD (the r4-proven TLP) with r7's halved LDS
// traffic (each A-frag read feeds 2 MFMAs). VGPR ~96 < 128 cap, no spill.
// B single-buffered: LOADB(h) issues before SMAX(h-1), latency hidden under
// softmax + other waves. den/num per (h,ct,r) dumped to LDS; final pass
// combines l-halves, applies the algebraic mask correction (masked h2 rows
// are zero -> exp2(0)=1 -> den-=nmask, num-=xms[d]), divides, reduces over d.
// ---------------------------------------------------------------------------
__global__ __launch_bounds__(512) void fused_mfma_kernel(
    const _Float16* __restrict__ h2f, const _Float16* __restrict__ w3t,
    const float* __restrict__ xT, const float* __restrict__ xms,
    const float* __restrict__ nmask, const float* __restrict__ tbias,
    float* __restrict__ out) {
  __shared__ _Float16 aLDS[128 * 128];     // 32 KB, slot-swizzled
  __shared__ float wp[8][NH][2][16][2];    // [wave][h][ct][r][den,num] 32 KB
  const int n = blockIdx.x, hg = blockIdx.y;
  const int tid = threadIdx.x;
  const int wid = tid >> 6, lane = tid & 63;
  const int r = lane & 15, kg = lane >> 4;
  const int wset = wid & 3;       // column group: cols [wset*32, +32)
  const int H = wid >> 2;         // l-half: rows [H*64, +64)

  // stage h2[n] (fp16, 32 KB) into LDS, swizzling 16B slots: dsl = sl^(row&7)
  const _Float16* h2n = h2f + (size_t)n * 16384;
  {
    char* lb = (char*)aLDS;
#pragma unroll
    for (int i = 0; i < 4; ++i) {
      const int og = (tid + 512 * i) * 16;  // linear global byte offset
      const int row = og >> 8;              // 256 B per row (128 fp16)
      const int sl = (og >> 4) & 15;        // 16B slot in row
      const float4 v = *(const float4*)((const char*)h2n + og);
      *(float4*)(lb + row * 256 + (sl ^ (row & 7)) * 16) = v;
    }
  }

  // this lane's x values: x[l, d] for l = H*64 + rt*16 + kg*4 + j,
  // d = wset*32 + ct*16 + r; reused across all h
  f4v xv[2][4];
#pragma unroll
  for (int ct = 0; ct < 2; ++ct) {
    const float* xc = xT + (size_t)n * 16384 +
                      (size_t)(wset * 32 + ct * 16 + r) * 128 + H * 64 + kg * 4;
#pragma unroll
    for (int rt = 0; rt < 4; ++rt) xv[ct][rt] = *(const f4v*)(xc + rt * 16);
  }

  __syncthreads();

  const char* lb = (const char*)aLDS;
  int dsl[4];
#pragma unroll
  for (int ks = 0; ks < 4; ++ks) dsl[ks] = ((ks * 4 + kg) ^ (r & 7)) * 16;
  const int rowBase = (H * 64 + r) * 256;

  // B base for this lane; per-h stride is 128*128 fp16
  const _Float16* w3g =
      w3t + ((size_t)(hg * NH) * 128 + wset * 32 + r) * 128 + kg * 8;

  hfrag b[4][2];
  f4v acc[4][2];

#define LOADB(h)                                                          \
  do {                                                                    \
    const _Float16* _p = w3g + (size_t)(h) * 16384;                       \
    _Pragma("unroll") for (int ks = 0; ks < 4; ++ks) {                    \
      b[ks][0] = *(const hfrag*)(_p + ks * 32);                           \
      b[ks][1] = *(const hfrag*)(_p + 16 * 128 + ks * 32);                \
    }                                                                     \
  } while (0)

#define MFMA_GRP()                                                        \
  do {                                                                    \
    _Pragma("unroll") for (int rt = 0; rt < 4; ++rt) {                    \
      f4v _z = {0.f, 0.f, 0.f, 0.f};                                      \
      hfrag _a = *(const hfrag*)(lb + rowBase + rt * 16 * 256 + dsl[0]);  \
      acc[rt][0] =                                                        \
          __builtin_amdgcn_mfma_f32_16x16x32_f16(_a, b[0][0], _z, 0, 0, 0);\
      acc[rt][1] =                                                        \
          __builtin_amdgcn_mfma_f32_16x16x32_f16(_a, b[0][1], _z, 0, 0, 0);\
    }                                                                     \
    _Pragma("unroll") for (int ks = 1; ks < 4; ++ks)                      \
        _Pragma("unroll") for (int rt = 0; rt < 4; ++rt) {                \
      hfrag _a = *(const hfrag*)(lb + rowBase + rt * 16 * 256 + dsl[ks]); \
      acc[rt][0] = __builtin_amdgcn_mfma_f32_16x16x32_f16(_a, b[ks][0],   \
                                                          acc[rt][0], 0, 0, 0);\
      acc[rt][1] = __builtin_amdgcn_mfma_f32_16x16x32_f16(_a, b[ks][1],   \
                                                          acc[rt][1], 0, 0, 0);\
    }                                                                     \
  } while (0)

#define SMAX(h)                                                           \
  do {                                                                    \
    _Pragma("unroll") for (int ct = 0; ct < 2; ++ct) {                    \
      float den0 = 0.f, den1 = 0.f, num0 = 0.f, num1 = 0.f;               \
      _Pragma("unroll") for (int rt = 0; rt < 4; rt += 2) {               \
        _Pragma("unroll") for (int j = 0; j < 4; ++j) {                   \
          float e0 = __builtin_amdgcn_exp2f(acc[rt][ct][j]);              \
          float e1 = __builtin_amdgcn_exp2f(acc[rt + 1][ct][j]);          \
          den0 += e0;                                                     \
          num0 += e0 * xv[ct][rt][j];                                     \
          den1 += e1;                                                     \
          num1 += e1 * xv[ct][rt + 1][j];                                 \
        }                                                                 \
      }                                                                   \
      float den = den0 + den1, num = num0 + num1;                         \
      den += __shfl_xor(den, 16);                                         \
      den += __shfl_xor(den, 32);                                         \
      num += __shfl_xor(num, 16);                                         \
      num += __shfl_xor(num, 32);                                         \
      if (kg == 0) {                                                      \
        wp[wid][h][ct][r][0] = den;                                       \
        wp[wid][h][ct][r][1] = num;                                       \
      }                                                                   \
    }                                                                     \
  } while (0)

  // prologue
  LOADB(0);
  MFMA_GRP();  // h = 0
  // steady state: LOADB(h) hides under SMAX(h-1); b regs free after the
  // previous MFMA_GRP, acc freed by SMAX before MFMA_GRP rewrites it.
#pragma unroll 1
  for (int h = 1; h < NH; ++h) {
    LOADB(h);
    SMAX(h - 1);
    MFMA_GRP();
  }
  SMAX(NH - 1);

#undef LOADB
#undef MFMA_GRP
#undef SMAX

  __syncthreads();

  // final combine: threads [0,256): thread (h = tid>>4, r = tid&15); for
  // each of 8 col-slots combine the two l-halves, apply mask correction,
  // divide, accumulate; then fold the 16 r-lanes.
  if (tid < 16 * NH) {
    const int rr = tid & 15, hh = tid >> 4;  // hh 0..NH-1
    const float nm = nmask[n];
    const float* xmn = xms + n * 128;
    float s = 0.f;
#pragma unroll
    for (int ws = 0; ws < 4; ++ws)
#pragma unroll
      for (int ct = 0; ct < 2; ++ct) {
        const int d = ws * 32 + ct * 16 + rr;
        float den = wp[ws][hh][ct][rr][0] + wp[ws + 4][hh][ct][rr][0] - nm;
        float num = wp[ws][hh][ct][rr][1] + wp[ws + 4][hh][ct][rr][1] - xmn[d];
        s += num * __builtin_amdgcn_rcpf(den);
      }
    s += __shfl_xor(s, 1);
    s += __shfl_xor(s, 2);
    s += __shfl_xor(s, 4);
    s += __shfl_xor(s, 8);
    if (rr == 0) {
      const int h = hg * NH + hh;
      out[n * 128 + h] = fmaxf(s + tbias[h], 0.f);
    }
  }
}

// ---------------------------------------------------------------------------
extern "C" void kernel_launch(void* const* d_in, const int* in_sizes, int n_in,
                              void* d_out, int out_size, void* d_ws,
                              size_t ws_size, hipStream_t stream) {
  (void)in_sizes; (void)n_in; (void)out_size; (void)ws_size;
  const float* x     = (const float*)d_in[0];
  const float* maskx = (const float*)d_in[1];
  const float* W1    = (const float*)d_in[2];
  const float* b1    = (const float*)d_in[3];
  const float* W2    = (const float*)d_in[4];
  const float* b2    = (const float*)d_in[5];
  const float* W3    = (const float*)d_in[6];
  // d_in[7] = b3: constant along the softmax (L) axis -> cancels, unused.
  const float* tbias = (const float*)d_in[8];
  float* out = (float*)d_out;

  char* ws = (char*)d_ws;
  _Float16* w3t   = (_Float16*)ws;                          // 4 MB @ 0
  _Float16* h2f   = (_Float16*)(ws + (4u << 20));           // 2 MB @ 4M
  float*    xms   = (float*)(ws + (6u << 20));              // 32 KB @ 6M
  float*    nmask = (float*)(ws + (6u << 20) + (64u << 10));// 256 B
  float*    xT    = (float*)(ws + (8u << 20));              // 4 MB @ 8M

  prep_kernel<<<3136, 256, 0, stream>>>(W3, w3t, x, xT, maskx, xms, nmask);
  mlp2_kernel<<<dim3(64, 4), 256, 0, stream>>>(x, W1, b1, W2, b2, maskx, h2f);
  fused_mfma_kernel<<<dim3(64, 8), 512, 0, stream>>>(h2f, w3t, xT, xms,
                                                     nmask, tbias, out);
}

// Round 9
// 94.189 us; speedup vs baseline: 1.0898x; 1.0898x over previous
//
#include <hip/hip_runtime.h>

#define NH 16

using hfrag = __attribute__((ext_vector_type(8))) _Float16;
using f4v   = __attribute__((ext_vector_type(4))) float;

// ---------------------------------------------------------------------------
// Merged prep:
//   blocks [0,2048):    W3 (128k x 16384f f32) -> w3t (16384f x 128k fp16,
//                       pre-scaled by log2e so softmax uses raw v_exp_f32)
//   blocks [2048,3072): x -> xT
//   blocks [3072,3136): xms[n,d] = sum_{l masked} x[n,l,d], nmask[n] = #masked
// ---------------------------------------------------------------------------
__global__ __launch_bounds__(256) void prep_kernel(
    const float* __restrict__ W3, _Float16* __restrict__ w3t,
    const float* __restrict__ x, float* __restrict__ xT,
    const float* __restrict__ maskx, float* __restrict__ xms,
    float* __restrict__ nmask) {
  __shared__ float t[32][33];
  __shared__ float sm2[2][128];
  const int bid = blockIdx.x;
  const int tx = threadIdx.x & 31, ty = threadIdx.x >> 5;  // ty 0..7
  if (bid < 2048) {
    const int f0 = (bid & 511) * 32;
    const int k0 = (bid >> 9) * 32;
#pragma unroll
    for (int i = 0; i < 4; ++i)
      t[ty + 8 * i][tx] = W3[(size_t)(k0 + ty + 8 * i) * 16384 + f0 + tx];
    __syncthreads();
#pragma unroll
    for (int i = 0; i < 4; ++i)
      w3t[(size_t)(f0 + ty + 8 * i) * 128 + k0 + tx] =
          (_Float16)(t[tx][ty + 8 * i] * 1.44269504f);
  } else if (bid < 3072) {
    const int b2 = bid - 2048;
    const int d0 = (b2 & 3) * 32, l0 = ((b2 >> 2) & 3) * 32, n = b2 >> 4;
    const size_t base = (size_t)n * 16384;
#pragma unroll
    for (int i = 0; i < 4; ++i)
      t[ty + 8 * i][tx] = x[base + (size_t)(l0 + ty + 8 * i) * 128 + d0 + tx];
    __syncthreads();
#pragma unroll
    for (int i = 0; i < 4; ++i)
      xT[base + (size_t)(d0 + ty + 8 * i) * 128 + l0 + tx] = t[tx][ty + 8 * i];
  } else {
    const int n = bid - 3072;
    const int d = threadIdx.x & 127, seg = threadIdx.x >> 7;
    const float* xn = x + (size_t)n * 16384;
    const float* mn = maskx + n * 128;
    float acc = 0.f;
#pragma unroll 8
    for (int l = seg * 64; l < seg * 64 + 64; ++l)
      acc += (mn[l] == 0.f) ? xn[l * 128 + d] : 0.f;
    sm2[seg][d] = acc;
    __syncthreads();
    if (threadIdx.x < 128) xms[n * 128 + d] = sm2[0][d] + sm2[1][d];
    if (threadIdx.x == 0) {
      float c = 0.f;
      for (int l = 0; l < 128; ++l) c += (mn[l] == 0.f) ? 1.f : 0.f;
      nmask[n] = c;
    }
  }
}

// ---------------------------------------------------------------------------
// MLP: h2 = relu(relu(x@W1+b1)@W2+b2) * mask -> fp16. Masked l-rows are
// zeroed here so the fused kernel needs no per-element mask logic.
// grid (64 n, 4 lq), 256 thr.
// ---------------------------------------------------------------------------
__global__ __launch_bounds__(256) void mlp2_kernel(
    const float* __restrict__ x, const float* __restrict__ W1,
    const float* __restrict__ b1, const float* __restrict__ W2,
    const float* __restrict__ b2, const float* __restrict__ maskx,
    _Float16* __restrict__ h2f) {
  __shared__ float wbuf[128 * 128];   // 64 KB weights
  __shared__ float abuf[32 * 132];    // padded activations
  const int n = blockIdx.x, lq = blockIdx.y;
  const int tid = threadIdx.x;

  {
    const float4* wsrc = (const float4*)W1;
    float4* wdst = (float4*)wbuf;
#pragma unroll
    for (int i = 0; i < 16; ++i) wdst[tid + 256 * i] = wsrc[tid + 256 * i];
    const float4* xsrc = (const float4*)(x + (size_t)n * 16384 + lq * 32 * 128);
#pragma unroll
    for (int i = 0; i < 4; ++i) {
      int idx = tid + 256 * i;
      int row = idx >> 5, c4 = idx & 31;
      *(float4*)&abuf[row * 132 + c4 * 4] = xsrc[idx];
    }
  }
  __syncthreads();

  const int tl = tid >> 4, td = tid & 15;
  const int r0 = tl * 2, j0 = td * 8;
  const float m0 = maskx[n * 128 + lq * 32 + r0 + 0];
  const float m1 = maskx[n * 128 + lq * 32 + r0 + 1];
  float s[2][8];

#pragma unroll
  for (int i = 0; i < 2; ++i)
#pragma unroll
    for (int j = 0; j < 8; ++j) s[i][j] = 0.f;
#pragma unroll 4
  for (int k = 0; k < 128; ++k) {
    float a0 = abuf[(r0 + 0) * 132 + k];
    float a1 = abuf[(r0 + 1) * 132 + k];
    float4 bv0 = *(const float4*)&wbuf[k * 128 + j0];
    float4 bv1 = *(const float4*)&wbuf[k * 128 + j0 + 4];
    float b[8] = {bv0.x, bv0.y, bv0.z, bv0.w, bv1.x, bv1.y, bv1.z, bv1.w};
#pragma unroll
    for (int j = 0; j < 8; ++j) {
      s[0][j] += a0 * b[j];
      s[1][j] += a1 * b[j];
    }
  }
  __syncthreads();

#pragma unroll
  for (int i = 0; i < 2; ++i)
#pragma unroll
    for (int j = 0; j < 8; ++j)
      abuf[(r0 + i) * 132 + j0 + j] = fmaxf(s[i][j] + b1[j0 + j], 0.f);
  {
    const float4* wsrc = (const float4*)W2;
    float4* wdst = (float4*)wbuf;
#pragma unroll
    for (int i = 0; i < 16; ++i) wdst[tid + 256 * i] = wsrc[tid + 256 * i];
  }
  __syncthreads();

#pragma unroll
  for (int i = 0; i < 2; ++i)
#pragma unroll
    for (int j = 0; j < 8; ++j) s[i][j] = 0.f;
#pragma unroll 4
  for (int k = 0; k < 128; ++k) {
    float a0 = abuf[(r0 + 0) * 132 + k];
    float a1 = abuf[(r0 + 1) * 132 + k];
    float4 bv0 = *(const float4*)&wbuf[k * 128 + j0];
    float4 bv1 = *(const float4*)&wbuf[k * 128 + j0 + 4];
    float b[8] = {bv0.x, bv0.y, bv0.z, bv0.w, bv1.x, bv1.y, bv1.z, bv1.w};
#pragma unroll
    for (int j = 0; j < 8; ++j) {
      s[0][j] += a0 * b[j];
      s[1][j] += a1 * b[j];
    }
  }

  const float mm[2] = {m0, m1};
  const size_t obase = (size_t)n * 16384 + (size_t)(lq * 32) * 128;
#pragma unroll
  for (int i = 0; i < 2; ++i)
#pragma unroll
    for (int j = 0; j < 8; ++j)
      h2f[obase + (size_t)(r0 + i) * 128 + j0 + j] =
          (_Float16)(fmaxf(s[i][j] + b2[j0 + j], 0.f) * mm[i]);
}

// ---------------------------------------------------------------------------
// Fused: 256 thr = 4 waves; each wave owns 32 d-cols (2 ct) x full 128 l.
// B (w3t) loaded ONCE per block per h (r4 property); each A-frag LDS read
// feeds 2 MFMAs (r8 property) -> 4096 A-reads/CU ~ 20 us LDS floor.
// 256-thr blocks lift the 512-thr 128-VGPR cap (m97 precedent: 164 VGPR),
// so acc[8][2]+xv[2][8]+b[4][2] (~185 VGPR) stay in registers. grid
// (8 hg, 64 n): hg is the fast axis so each XCD's L2 keeps one 512 KB w3t
// slice. Each wave's den/num are complete (full l) -> per-wave scalar
// partial in wp[4][NH]; mask correction algebraic (masked h2 rows zero ->
// exp2(0)=1 -> den-=nmask, num-=xms[d]).
// ---------------------------------------------------------------------------
__global__ __launch_bounds__(256) void fused_mfma_kernel(
    const _Float16* __restrict__ h2f, const _Float16* __restrict__ w3t,
    const float* __restrict__ xT, const float* __restrict__ xms,
    const float* __restrict__ nmask, const float* __restrict__ tbias,
    float* __restrict__ out) {
  __shared__ _Float16 aLDS[128 * 128];   // 32 KB, slot-swizzled
  __shared__ float wp[4][NH];            // per-wave per-h scalar partials
  const int hg = blockIdx.x, n = blockIdx.y;
  const int tid = threadIdx.x;
  const int wid = tid >> 6, lane = tid & 63;   // wid 0..3: cols [wid*32,+32)
  const int r = lane & 15, kg = lane >> 4;

  // stage h2[n] (fp16, 32 KB) into LDS, swizzling 16B slots: dsl = sl^(row&7)
  const _Float16* h2n = h2f + (size_t)n * 16384;
  {
    char* lb = (char*)aLDS;
#pragma unroll
    for (int i = 0; i < 8; ++i) {
      const int og = (tid + 256 * i) * 16;  // linear global byte offset
      const int row = og >> 8;              // 256 B per row (128 fp16)
      const int sl = (og >> 4) & 15;        // 16B slot in row
      const float4 v = *(const float4*)((const char*)h2n + og);
      *(float4*)(lb + row * 256 + (sl ^ (row & 7)) * 16) = v;
    }
  }

  // this lane's x columns (d = wid*32 + ct*16 + r), full l, all h reuse
  f4v xv[2][8];
  float xm[2];
#pragma unroll
  for (int ct = 0; ct < 2; ++ct) {
    const float* xc = xT + (size_t)n * 16384 +
                      (size_t)(wid * 32 + ct * 16 + r) * 128 + kg * 4;
#pragma unroll
    for (int rt = 0; rt < 8; ++rt) xv[ct][rt] = *(const f4v*)(xc + rt * 16);
    xm[ct] = xms[n * 128 + wid * 32 + ct * 16 + r];
  }
  const float nm = nmask[n];

  __syncthreads();

  const char* lb = (const char*)aLDS;
  int dsl[4];
#pragma unroll
  for (int ks = 0; ks < 4; ++ks) dsl[ks] = ((ks * 4 + kg) ^ (r & 7)) * 16;

  // B base for this lane; per-h stride is 128*128 fp16
  const _Float16* w3g =
      w3t + ((size_t)(hg * NH) * 128 + wid * 32 + r) * 128 + kg * 8;

  hfrag b[4][2];
  f4v acc[8][2];

#define LOADB(h)                                                          \
  do {                                                                    \
    const _Float16* _p = w3g + (size_t)(h) * 16384;                       \
    _Pragma("unroll") for (int ks = 0; ks < 4; ++ks) {                    \
      b[ks][0] = *(const hfrag*)(_p + ks * 32);                           \
      b[ks][1] = *(const hfrag*)(_p + 16 * 128 + ks * 32);                \
    }                                                                     \
  } while (0)

#define MFMA_GRP()                                                        \
  do {                                                                    \
    _Pragma("unroll") for (int rt = 0; rt < 8; ++rt) {                    \
      f4v _z = {0.f, 0.f, 0.f, 0.f};                                      \
      hfrag _a = *(const hfrag*)(lb + (rt * 16 + r) * 256 + dsl[0]);      \
      acc[rt][0] =                                                        \
          __builtin_amdgcn_mfma_f32_16x16x32_f16(_a, b[0][0], _z, 0, 0, 0);\
      acc[rt][1] =                                                        \
          __builtin_amdgcn_mfma_f32_16x16x32_f16(_a, b[0][1], _z, 0, 0, 0);\
    }                                                                     \
    _Pragma("unroll") for (int ks = 1; ks < 4; ++ks)                      \
        _Pragma("unroll") for (int rt = 0; rt < 8; ++rt) {                \
      hfrag _a = *(const hfrag*)(lb + (rt * 16 + r) * 256 + dsl[ks]);     \
      acc[rt][0] = __builtin_amdgcn_mfma_f32_16x16x32_f16(_a, b[ks][0],   \
                                                          acc[rt][0], 0, 0, 0);\
      acc[rt][1] = __builtin_amdgcn_mfma_f32_16x16x32_f16(_a, b[ks][1],   \
                                                          acc[rt][1], 0, 0, 0);\
    }                                                                     \
  } while (0)

#define SMAX(h)                                                           \
  do {                                                                    \
    float pcs = 0.f;                                                      \
    _Pragma("unroll") for (int ct = 0; ct < 2; ++ct) {                    \
      float den0 = 0.f, den1 = 0.f, num0 = 0.f, num1 = 0.f;               \
      _Pragma("unroll") for (int rt = 0; rt < 8; rt += 2) {               \
        _Pragma("unroll") for (int j = 0; j < 4; ++j) {                   \
          float e0 = __builtin_amdgcn_exp2f(acc[rt][ct][j]);              \
          float e1 = __builtin_amdgcn_exp2f(acc[rt + 1][ct][j]);          \
          den0 += e0;                                                     \
          num0 += e0 * xv[ct][rt][j];                                     \
          den1 += e1;                                                     \
          num1 += e1 * xv[ct][rt + 1][j];                                 \
        }                                                                 \
      }                                                                   \
      float den = den0 + den1, num = num0 + num1;                         \
      den += __shfl_xor(den, 16);                                         \
      den += __shfl_xor(den, 32);                                         \
      num += __shfl_xor(num, 16);                                         \
      num += __shfl_xor(num, 32);                                         \
      den -= nm;                                                          \
      num -= xm[ct];                                                      \
      pcs += num * __builtin_amdgcn_rcpf(den);                            \
    }                                                                     \
    pcs += __shfl_xor(pcs, 1);                                            \
    pcs += __shfl_xor(pcs, 2);                                            \
    pcs += __shfl_xor(pcs, 4);                                            \
    pcs += __shfl_xor(pcs, 8);                                            \
    if (lane == 0) wp[wid][h] = pcs;                                      \
  } while (0)

  // prologue
  LOADB(0);
  MFMA_GRP();  // h = 0
  // steady state: LOADB(h) issues before SMAX(h-1) so its L2/L3 latency
  // hides under the softmax VALU work; b regs are WAR-free after the
  // previous MFMA_GRP issued, acc freed by SMAX before MFMA_GRP rewrites.
#pragma unroll 1
  for (int h = 1; h < NH; ++h) {
    LOADB(h);
    SMAX(h - 1);
    MFMA_GRP();
  }
  SMAX(NH - 1);

#undef LOADB
#undef MFMA_GRP
#undef SMAX

  __syncthreads();
  if (tid < NH) {
    const float s = wp[0][tid] + wp[1][tid] + wp[2][tid] + wp[3][tid];
    const int h = hg * NH + tid;
    out[n * 128 + h] = fmaxf(s + tbias[h], 0.f);
  }
}

// ---------------------------------------------------------------------------
extern "C" void kernel_launch(void* const* d_in, const int* in_sizes, int n_in,
                              void* d_out, int out_size, void* d_ws,
                              size_t ws_size, hipStream_t stream) {
  (void)in_sizes; (void)n_in; (void)out_size; (void)ws_size;
  const float* x     = (const float*)d_in[0];
  const float* maskx = (const float*)d_in[1];
  const float* W1    = (const float*)d_in[2];
  const float* b1    = (const float*)d_in[3];
  const float* W2    = (const float*)d_in[4];
  const float* b2    = (const float*)d_in[5];
  const float* W3    = (const float*)d_in[6];
  // d_in[7] = b3: constant along the softmax (L) axis -> cancels, unused.
  const float* tbias = (const float*)d_in[8];
  float* out = (float*)d_out;

  char* ws = (char*)d_ws;
  _Float16* w3t   = (_Float16*)ws;                          // 4 MB @ 0
  _Float16* h2f   = (_Float16*)(ws + (4u << 20));           // 2 MB @ 4M
  float*    xms   = (float*)(ws + (6u << 20));              // 32 KB @ 6M
  float*    nmask = (float*)(ws + (6u << 20) + (64u << 10));// 256 B
  float*    xT    = (float*)(ws + (8u << 20));              // 4 MB @ 8M

  prep_kernel<<<3136, 256, 0, stream>>>(W3, w3t, x, xT, maskx, xms, nmask);
  mlp2_kernel<<<dim3(64, 4), 256, 0, stream>>>(x, W1, b1, W2, b2, maskx, h2f);
  fused_mfma_kernel<<<dim3(8, 64), 256, 0, stream>>>(h2f, w3t, xT, xms,
                                                     nmask, tbias, out);
}

// Round 10
// 79.973 us; speedup vs baseline: 1.2836x; 1.1778x over previous
//
#include <hip/hip_runtime.h>

#define NH 32

using hfrag = __attribute__((ext_vector_type(8))) _Float16;
using f4v   = __attribute__((ext_vector_type(4))) float;

// ---------------------------------------------------------------------------
// Merged prep:
//   blocks [0,2048):    W3 (128k x 16384f f32) -> w3t (16384f x 128k fp16,
//                       pre-scaled by log2e so softmax uses raw v_exp_f32)
//   blocks [2048,3072): x -> xT
//   blocks [3072,3136): xms[n,d] = sum_{l masked} x[n,l,d], nmask[n] = #masked
// ---------------------------------------------------------------------------
__global__ __launch_bounds__(256) void prep_kernel(
    const float* __restrict__ W3, _Float16* __restrict__ w3t,
    const float* __restrict__ x, float* __restrict__ xT,
    const float* __restrict__ maskx, float* __restrict__ xms,
    float* __restrict__ nmask) {
  __shared__ float t[32][33];
  __shared__ float sm2[2][128];
  const int bid = blockIdx.x;
  const int tx = threadIdx.x & 31, ty = threadIdx.x >> 5;  // ty 0..7
  if (bid < 2048) {
    const int f0 = (bid & 511) * 32;
    const int k0 = (bid >> 9) * 32;
#pragma unroll
    for (int i = 0; i < 4; ++i)
      t[ty + 8 * i][tx] = W3[(size_t)(k0 + ty + 8 * i) * 16384 + f0 + tx];
    __syncthreads();
#pragma unroll
    for (int i = 0; i < 4; ++i)
      w3t[(size_t)(f0 + ty + 8 * i) * 128 + k0 + tx] =
          (_Float16)(t[tx][ty + 8 * i] * 1.44269504f);
  } else if (bid < 3072) {
    const int b2 = bid - 2048;
    const int d0 = (b2 & 3) * 32, l0 = ((b2 >> 2) & 3) * 32, n = b2 >> 4;
    const size_t base = (size_t)n * 16384;
#pragma unroll
    for (int i = 0; i < 4; ++i)
      t[ty + 8 * i][tx] = x[base + (size_t)(l0 + ty + 8 * i) * 128 + d0 + tx];
    __syncthreads();
#pragma unroll
    for (int i = 0; i < 4; ++i)
      xT[base + (size_t)(d0 + ty + 8 * i) * 128 + l0 + tx] = t[tx][ty + 8 * i];
  } else {
    const int n = bid - 3072;
    const int d = threadIdx.x & 127, seg = threadIdx.x >> 7;
    const float* xn = x + (size_t)n * 16384;
    const float* mn = maskx + n * 128;
    float acc = 0.f;
#pragma unroll 8
    for (int l = seg * 64; l < seg * 64 + 64; ++l)
      acc += (mn[l] == 0.f) ? xn[l * 128 + d] : 0.f;
    sm2[seg][d] = acc;
    __syncthreads();
    if (threadIdx.x < 128) xms[n * 128 + d] = sm2[0][d] + sm2[1][d];
    if (threadIdx.x == 0) {
      float c = 0.f;
      for (int l = 0; l < 128; ++l) c += (mn[l] == 0.f) ? 1.f : 0.f;
      nmask[n] = c;
    }
  }
}

// ---------------------------------------------------------------------------
// MLP: h2 = relu(relu(x@W1+b1)@W2+b2) * mask -> fp16. Masked l-rows are
// zeroed here so the fused kernel needs no per-element mask logic.
// grid (64 n, 4 lq), 256 thr.
// ---------------------------------------------------------------------------
__global__ __launch_bounds__(256) void mlp2_kernel(
    const float* __restrict__ x, const float* __restrict__ W1,
    const float* __restrict__ b1, const float* __restrict__ W2,
    const float* __restrict__ b2, const float* __restrict__ maskx,
    _Float16* __restrict__ h2f) {
  __shared__ float wbuf[128 * 128];   // 64 KB weights
  __shared__ float abuf[32 * 132];    // padded activations
  const int n = blockIdx.x, lq = blockIdx.y;
  const int tid = threadIdx.x;

  {
    const float4* wsrc = (const float4*)W1;
    float4* wdst = (float4*)wbuf;
#pragma unroll
    for (int i = 0; i < 16; ++i) wdst[tid + 256 * i] = wsrc[tid + 256 * i];
    const float4* xsrc = (const float4*)(x + (size_t)n * 16384 + lq * 32 * 128);
#pragma unroll
    for (int i = 0; i < 4; ++i) {
      int idx = tid + 256 * i;
      int row = idx >> 5, c4 = idx & 31;
      *(float4*)&abuf[row * 132 + c4 * 4] = xsrc[idx];
    }
  }
  __syncthreads();

  const int tl = tid >> 4, td = tid & 15;
  const int r0 = tl * 2, j0 = td * 8;
  const float m0 = maskx[n * 128 + lq * 32 + r0 + 0];
  const float m1 = maskx[n * 128 + lq * 32 + r0 + 1];
  float s[2][8];

#pragma unroll
  for (int i = 0; i < 2; ++i)
#pragma unroll
    for (int j = 0; j < 8; ++j) s[i][j] = 0.f;
#pragma unroll 4
  for (int k = 0; k < 128; ++k) {
    float a0 = abuf[(r0 + 0) * 132 + k];
    float a1 = abuf[(r0 + 1) * 132 + k];
    float4 bv0 = *(const float4*)&wbuf[k * 128 + j0];
    float4 bv1 = *(const float4*)&wbuf[k * 128 + j0 + 4];
    float b[8] = {bv0.x, bv0.y, bv0.z, bv0.w, bv1.x, bv1.y, bv1.z, bv1.w};
#pragma unroll
    for (int j = 0; j < 8; ++j) {
      s[0][j] += a0 * b[j];
      s[1][j] += a1 * b[j];
    }
  }
  __syncthreads();

#pragma unroll
  for (int i = 0; i < 2; ++i)
#pragma unroll
    for (int j = 0; j < 8; ++j)
      abuf[(r0 + i) * 132 + j0 + j] = fmaxf(s[i][j] + b1[j0 + j], 0.f);
  {
    const float4* wsrc = (const float4*)W2;
    float4* wdst = (float4*)wbuf;
#pragma unroll
    for (int i = 0; i < 16; ++i) wdst[tid + 256 * i] = wsrc[tid + 256 * i];
  }
  __syncthreads();

#pragma unroll
  for (int i = 0; i < 2; ++i)
#pragma unroll
    for (int j = 0; j < 8; ++j) s[i][j] = 0.f;
#pragma unroll 4
  for (int k = 0; k < 128; ++k) {
    float a0 = abuf[(r0 + 0) * 132 + k];
    float a1 = abuf[(r0 + 1) * 132 + k];
    float4 bv0 = *(const float4*)&wbuf[k * 128 + j0];
    float4 bv1 = *(const float4*)&wbuf[k * 128 + j0 + 4];
    float b[8] = {bv0.x, bv0.y, bv0.z, bv0.w, bv1.x, bv1.y, bv1.z, bv1.w};
#pragma unroll
    for (int j = 0; j < 8; ++j) {
      s[0][j] += a0 * b[j];
      s[1][j] += a1 * b[j];
    }
  }

  const float mm[2] = {m0, m1};
  const size_t obase = (size_t)n * 16384 + (size_t)(lq * 32) * 128;
#pragma unroll
  for (int i = 0; i < 2; ++i)
#pragma unroll
    for (int j = 0; j < 8; ++j)
      h2f[obase + (size_t)(r0 + i) * 128 + j0 + j] =
          (_Float16)(fmaxf(s[i][j] + b2[j0 + j], 0.f) * mm[i]);
}

// ---------------------------------------------------------------------------
// Fused: 256 thr = 4 waves x 16 d-cols, full 128 l, 32 h; block covers the
// 64-col half dh of d. Full A tile hoisted to registers ONCE per block
// (af[4][8] = 128 VGPR; live set ~230 fits the 256-thr budget, m97
// precedent) -> ZERO LDS reads in the h-loop (the r4-r9 LDS wall, 20+ us,
// disappears). grid (8 g, 64 n), g=(hg,dh) fast -> XCD i is pinned to w3t
// slice g=i (id mod 8 = g): perfect L2 reuse; h2f/xT stream once from HBM.
// Each block writes per-(n,h) partials (sum over its 64 d of num/den);
// fin_kernel combines the two halves + bias + relu. Mask algebraic:
// masked h2 rows are zero -> exp2(0)=1 -> den-=nmask, num-=xms[d].
// ---------------------------------------------------------------------------
__global__ __launch_bounds__(256) void fused_mfma_kernel(
    const _Float16* __restrict__ h2f, const _Float16* __restrict__ w3t,
    const float* __restrict__ xT, const float* __restrict__ xms,
    const float* __restrict__ nmask, float* __restrict__ pout) {
  __shared__ _Float16 aLDS[128 * 128];   // 32 KB, slot-swizzled
  __shared__ float wp[4][NH];            // per-wave per-h scalar partials
  const int g = blockIdx.x, n = blockIdx.y;
  const int hg = g & 3, dh = g >> 2;
  const int tid = threadIdx.x;
  const int wid = tid >> 6, lane = tid & 63;
  const int r = lane & 15, kg = lane >> 4;
  const int d = dh * 64 + wid * 16 + r;  // this lane's d-column

  // stage h2[n] (fp16, 32 KB) into LDS, swizzling 16B slots: dsl = sl^(row&7)
  const _Float16* h2n = h2f + (size_t)n * 16384;
  {
    char* lb = (char*)aLDS;
#pragma unroll
    for (int i = 0; i < 8; ++i) {
      const int og = (tid + 256 * i) * 16;  // linear global byte offset
      const int row = og >> 8;              // 256 B per row (128 fp16)
      const int sl = (og >> 4) & 15;        // 16B slot in row
      const float4 v = *(const float4*)((const char*)h2n + og);
      *(float4*)(lb + row * 256 + (sl ^ (row & 7)) * 16) = v;
    }
  }

  // this lane's x column (full l), reused across all 32 h
  f4v xv[8];
  {
    const float* xc = xT + (size_t)n * 16384 + (size_t)d * 128 + kg * 4;
#pragma unroll
    for (int rt = 0; rt < 8; ++rt) xv[rt] = *(const f4v*)(xc + rt * 16);
  }
  const float xm = xms[n * 128 + d];
  const float nm = nmask[n];

  __syncthreads();

  // hoist the FULL A tile into registers: 32 frags = 128 VGPR, once/block
  hfrag af[4][8];
  {
    const char* lb = (const char*)aLDS;
#pragma unroll
    for (int ks = 0; ks < 4; ++ks) {
      const int dslByte = ((ks * 4 + kg) ^ (r & 7)) * 16;
#pragma unroll
      for (int rt = 0; rt < 8; ++rt)
        af[ks][rt] = *(const hfrag*)(lb + (rt * 16 + r) * 256 + dslByte);
    }
  }

  // B base for this lane; per-h stride is 128*128 fp16
  const _Float16* w3g =
      w3t + ((size_t)(hg * NH) * 128 + d) * 128 + kg * 8;

  hfrag b[4];
  f4v acc[8];

#define LOADB(h)                                                          \
  do {                                                                    \
    const _Float16* _p = w3g + (size_t)(h) * 16384;                       \
    _Pragma("unroll") for (int ks = 0; ks < 4; ++ks) b[ks] =              \
        *(const hfrag*)(_p + ks * 32);                                    \
  } while (0)

#define MFMA_GRP()                                                        \
  do {                                                                    \
    _Pragma("unroll") for (int rt = 0; rt < 8; ++rt) {                    \
      f4v _z = {0.f, 0.f, 0.f, 0.f};                                      \
      acc[rt] =                                                           \
          __builtin_amdgcn_mfma_f32_16x16x32_f16(af[0][rt], b[0], _z,     \
                                                 0, 0, 0);                \
    }                                                                     \
    _Pragma("unroll") for (int ks = 1; ks < 4; ++ks)                      \
        _Pragma("unroll") for (int rt = 0; rt < 8; ++rt) acc[rt] =        \
            __builtin_amdgcn_mfma_f32_16x16x32_f16(af[ks][rt], b[ks],     \
                                                   acc[rt], 0, 0, 0);     \
  } while (0)

#define SMAX(h)                                                           \
  do {                                                                    \
    float den0 = 0.f, den1 = 0.f, num0 = 0.f, num1 = 0.f;                 \
    _Pragma("unroll") for (int rt = 0; rt < 8; rt += 2) {                 \
      _Pragma("unroll") for (int j = 0; j < 4; ++j) {                     \
        float e0 = __builtin_amdgcn_exp2f(acc[rt][j]);                    \
        float e1 = __builtin_amdgcn_exp2f(acc[rt + 1][j]);                \
        den0 += e0;                                                       \
        num0 += e0 * xv[rt][j];                                           \
        den1 += e1;                                                       \
        num1 += e1 * xv[rt + 1][j];                                       \
      }                                                                   \
    }                                                                     \
    float den = den0 + den1, num = num0 + num1;                           \
    den += __shfl_xor(den, 16);                                           \
    den += __shfl_xor(den, 32);                                           \
    num += __shfl_xor(num, 16);                                           \
    num += __shfl_xor(num, 32);                                           \
    den -= nm;                                                            \
    num -= xm;                                                            \
    float pcs = num * __builtin_amdgcn_rcpf(den);                         \
    pcs += __shfl_xor(pcs, 1);                                            \
    pcs += __shfl_xor(pcs, 2);                                            \
    pcs += __shfl_xor(pcs, 4);                                            \
    pcs += __shfl_xor(pcs, 8);                                            \
    if (lane == 0) wp[wid][h] = pcs;                                      \
  } while (0)

  // prologue
  LOADB(0);
  MFMA_GRP();  // h = 0
  // steady state: LOADB(h) (L2-hit, XCD-pinned slice) issues before
  // SMAX(h-1) so its latency hides under the softmax; MFMA_GRP is pure
  // register work (af + b), no LDS.
#pragma unroll 1
  for (int h = 1; h < NH; ++h) {
    LOADB(h);
    SMAX(h - 1);
    MFMA_GRP();
  }
  SMAX(NH - 1);

#undef LOADB
#undef MFMA_GRP
#undef SMAX

  __syncthreads();
  if (tid < NH) {
    const float s = wp[0][tid] + wp[1][tid] + wp[2][tid] + wp[3][tid];
    pout[((size_t)n * 128 + hg * NH + tid) * 2 + dh] = s;
  }
}

// ---------------------------------------------------------------------------
// Finalize: combine the two d-halves, add bias, relu. 8192 outputs.
// ---------------------------------------------------------------------------
__global__ __launch_bounds__(256) void fin_kernel(
    const float* __restrict__ pout, const float* __restrict__ tbias,
    float* __restrict__ out) {
  const int idx = blockIdx.x * 256 + threadIdx.x;  // 0..8191
  const int h = idx & 127;
  out[idx] = fmaxf(pout[idx * 2] + pout[idx * 2 + 1] + tbias[h], 0.f);
}

// ---------------------------------------------------------------------------
extern "C" void kernel_launch(void* const* d_in, const int* in_sizes, int n_in,
                              void* d_out, int out_size, void* d_ws,
                              size_t ws_size, hipStream_t stream) {
  (void)in_sizes; (void)n_in; (void)out_size; (void)ws_size;
  const float* x     = (const float*)d_in[0];
  const float* maskx = (const float*)d_in[1];
  const float* W1    = (const float*)d_in[2];
  const float* b1    = (const float*)d_in[3];
  const float* W2    = (const float*)d_in[4];
  const float* b2    = (const float*)d_in[5];
  const float* W3    = (const float*)d_in[6];
  // d_in[7] = b3: constant along the softmax (L) axis -> cancels, unused.
  const float* tbias = (const float*)d_in[8];
  float* out = (float*)d_out;

  char* ws = (char*)d_ws;
  _Float16* w3t   = (_Float16*)ws;                           // 4 MB @ 0
  _Float16* h2f   = (_Float16*)(ws + (4u << 20));            // 2 MB @ 4M
  float*    xms   = (float*)(ws + (6u << 20));               // 32 KB @ 6M
  float*    nmask = (float*)(ws + (6u << 20) + (64u << 10)); // 256 B
  float*    pout  = (float*)(ws + (6u << 20) + (128u << 10));// 64 KB
  float*    xT    = (float*)(ws + (8u << 20));               // 4 MB @ 8M

  prep_kernel<<<3136, 256, 0, stream>>>(W3, w3t, x, xT, maskx, xms, nmask);
  mlp2_kernel<<<dim3(64, 4), 256, 0, stream>>>(x, W1, b1, W2, b2, maskx, h2f);
  fused_mfma_kernel<<<dim3(8, 64), 256, 0, stream>>>(h2f, w3t, xT, xms,
                                                     nmask, pout);
  fin_kernel<<<32, 256, 0, stream>>>(pout, tbias, out);
}